// Round 9
// baseline (294.142 us; speedup 1.0000x reference)
//
#include <hip/hip_runtime.h>
#include <hip/hip_bf16.h>
#include <hip/hip_cooperative_groups.h>

namespace cg = cooperative_groups;

#define B_ 32
#define C_ 64
#define N_ 16384
constexpr float BN_INV = 1.0f / (32.0f * 16384.0f);   // 1/(B*N)

typedef float f32x4 __attribute__((ext_vector_type(4)));
typedef short s16x8 __attribute__((ext_vector_type(8)));

// ---- workspace layout (float offsets) ----
constexpr size_t WS_GPART = 0;                               // [512][4096] chunk Gram partials (mega uses 256 rows)
constexpr size_t WS_RPART = WS_GPART + (size_t)512 * 4096;   // [512][64]
constexpr size_t WS_G     = WS_RPART + (size_t)512 * 64;     // [32][4096]
constexpr size_t WS_RB    = WS_G + (size_t)32 * 4096;        // [32][64]
constexpr size_t WS_V     = WS_RB + (size_t)32 * 64;         // [32][16384]
constexpr size_t WS_W     = WS_V + (size_t)32 * N_;          // [32][64]

__device__ constexpr int P1I[10] = {0,0,0,0,1,1,1,2,2,3};
__device__ constexpr int P1J[10] = {0,1,2,3,1,2,3,2,3,3};
__device__ constexpr int P1AT[4][4] = {{0,1,2,3},{1,4,5,6},{2,5,7,8},{3,6,8,9}};

__device__ __forceinline__ unsigned short bf16_rne_s(float f) {
    unsigned u = __float_as_uint(f);
    unsigned r = u + 0x7FFFu + ((u >> 16) & 1u);
    return (unsigned short)(r >> 16);
}
__device__ __forceinline__ void cvt8hi(const f32x4& a, const f32x4& b, s16x8& hi) {
    float f[8] = {a[0], a[1], a[2], a[3], b[0], b[1], b[2], b[3]};
    #pragma unroll
    for (int j = 0; j < 8; ++j) hi[j] = (short)bf16_rne_s(f[j]);
}

// ===================== MEGA: fused cooperative pipeline =====================
// 256 blocks x 512 threads, 1 block/CU guaranteed (VGPR<=256 via bounds, LDS 63.7KB).
__global__ __launch_bounds__(512, 2) void mega(const float* __restrict__ x,
                                               const float* __restrict__ Wq,
                                               const float* __restrict__ gamma,
                                               const float* __restrict__ beta,
                                               const float* __restrict__ Wq2,
                                               const float* __restrict__ bq2,
                                               const float* __restrict__ Wsr,
                                               const float* __restrict__ bsr,
                                               const float* __restrict__ Wc,
                                               float* __restrict__ ws,
                                               float* __restrict__ out) {
    __shared__ __align__(16) unsigned char smem[63744];
    cg::grid_group grid = cg::this_grid();
    const int t = threadIdx.x;

    // ================= Phase A: Gram partials + v + rowsums =================
    {
        float* rawbF = (float*)smem;            // [4][2560]
        float* rwsF  = (float*)(smem + 40960);  // [8][64]
        const int wv = t >> 6, lane = t & 63;
        const int b = blockIdx.x >> 3, ch8 = blockIdx.x & 7;
        const int kg = lane >> 4, cl = lane & 15;
        const float* xb = x + ((size_t)b * C_ + cl) * N_ + ch8 * 2048 + kg * 8;

        f32x4 accP1[10];
        #pragma unroll
        for (int i = 0; i < 10; ++i) accP1[i] = (f32x4){0.f, 0.f, 0.f, 0.f};
        f32x4 rs = {0.f, 0.f, 0.f, 0.f};

        f32x4 cA[4], cB[4], nA[4], nB[4];
        #pragma unroll
        for (int g = 0; g < 4; ++g) {
            cA[g] = *(const f32x4*)(xb + (size_t)g * (16 * N_) + wv * 32);
            cB[g] = *(const f32x4*)(xb + (size_t)g * (16 * N_) + wv * 32 + 4);
        }

        for (int w = 0; w < 8; ++w) {
            if (w < 7) {
                const int noff = (8 * (w + 1) + wv) * 32;
                #pragma unroll
                for (int g = 0; g < 4; ++g) {
                    nA[g] = *(const f32x4*)(xb + (size_t)g * (16 * N_) + noff);
                    nB[g] = *(const f32x4*)(xb + (size_t)g * (16 * N_) + noff + 4);
                }
            }
            s16x8 hi[4];
            #pragma unroll
            for (int g = 0; g < 4; ++g) cvt8hi(cA[g], cB[g], hi[g]);

            f32x4 s0 = cA[0] + cA[1] + cA[2] + cA[3];
            f32x4 s1 = cB[0] + cB[1] + cB[2] + cB[3];
            #pragma unroll
            for (int m = 1; m <= 8; m <<= 1) {
                #pragma unroll
                for (int j = 0; j < 4; ++j) {
                    s0[j] += __shfl_xor(s0[j], m);
                    s1[j] += __shfl_xor(s1[j], m);
                }
            }
            if (cl == 0) {
                float* vp = ws + WS_V + (size_t)b * N_ + ch8 * 2048 + (8 * w + wv) * 32 + kg * 8;
                *(f32x4*)vp       = s0 * 0.015625f;
                *(f32x4*)(vp + 4) = s1 * 0.015625f;
            }
            #pragma unroll
            for (int g = 0; g < 4; ++g)
                rs[g] += cA[g][0] + cA[g][1] + cA[g][2] + cA[g][3]
                       + cB[g][0] + cB[g][1] + cB[g][2] + cB[g][3];

            #pragma unroll
            for (int i = 0; i < 10; ++i)
                accP1[i] = __builtin_amdgcn_mfma_f32_16x16x32_bf16(hi[P1I[i]], hi[P1J[i]], accP1[i], 0, 0, 0);

            #pragma unroll
            for (int g = 0; g < 4; ++g) { cA[g] = nA[g]; cB[g] = nB[g]; }
        }

        #pragma unroll
        for (int g = 0; g < 4; ++g) {
            rs[g] += __shfl_xor(rs[g], 16);
            rs[g] += __shfl_xor(rs[g], 32);
        }
        if (lane < 16) {
            #pragma unroll
            for (int g = 0; g < 4; ++g) rwsF[wv * 64 + g * 16 + lane] = rs[g];
        }

        if (wv < 4) {
            float* dst = rawbF + wv * 2560;
            #pragma unroll
            for (int i = 0; i < 10; ++i) *(f32x4*)(dst + i * 256 + lane * 4) = accP1[i];
        }
        __syncthreads();
        if (wv >= 4) {
            float* dst = rawbF + (wv - 4) * 2560;
            #pragma unroll
            for (int i = 0; i < 10; ++i) {
                f32x4 o = *(f32x4*)(dst + i * 256 + lane * 4);
                *(f32x4*)(dst + i * 256 + lane * 4) = o + accP1[i];
            }
        }
        __syncthreads();
        if (t < 64) {
            float s = 0.f;
            #pragma unroll
            for (int g = 0; g < 8; ++g) s += rwsF[g * 64 + t];
            ws[WS_RPART + (size_t)blockIdx.x * 64 + t] = s;
        }
        float* gp = ws + WS_GPART + (size_t)blockIdx.x * 4096;
        for (int e = t; e < 4096; e += 512) {
            const int r = e >> 6, c = e & 63;
            const int bi = r >> 4, bj = c >> 4, rr = r & 15, cc = c & 15;
            const int i1 = P1AT[bi][bj] * 256;
            const int o1 = (bi <= bj) ? (((rr >> 2) * 16 + cc) * 4 + (rr & 3))
                                      : (((cc >> 2) * 16 + rr) * 4 + (cc & 3));
            gp[e] = rawbF[0 * 2560 + i1 + o1] + rawbF[1 * 2560 + i1 + o1]
                  + rawbF[2 * 2560 + i1 + o1] + rawbF[3 * 2560 + i1 + o1];
        }
    }
    __threadfence();
    grid.sync();

    // ================= Phase B: reduce chunk partials =================
    {
        const int b = blockIdx.x >> 3, sl = blockIdx.x & 7;
        const int e = sl * 512 + t;
        float s = 0.f;
        #pragma unroll
        for (int chn = 0; chn < 8; ++chn) s += ws[WS_GPART + ((size_t)(b * 8 + chn)) * 4096 + e];
        ws[WS_G + (size_t)b * 4096 + e] = s;
        if (sl == 0 && t < 64) {
            float s2 = 0.f;
            #pragma unroll
            for (int chn = 0; chn < 8; ++chn) s2 += ws[WS_RPART + (size_t)(b * 8 + chn) * 64 + t];
            ws[WS_RB + b * 64 + t] = s2;
        }
    }
    __threadfence();
    grid.sync();

    // ================= Phase C: MFMA C×C algebra (blocks 0..31) =================
    if (blockIdx.x < 32) {
        const int bb = blockIdx.x;
        unsigned short* OPH0 = (unsigned short*)smem;
        unsigned short* OPH1 = OPH0 + 64 * 72;
        unsigned short* OPH2 = OPH1 + 64 * 72;
        float* F1 = (float*)(smem + 27648);
        float* F2 = (float*)(smem + 44288);
        float* SV = (float*)(smem + 60928);
        float *mS = SV, *muS = SV + 64, *DSv = SV + 128, *abv = SV + 192, *quadS = SV + 256,
              *rl = SV + 320, *ul = SV + 384, *avs = SV + 448, *sbv = SV + 512,
              *pls = SV + 576, *aml = SV + 640;
        const int w = t >> 6, lane = t & 63, cl = lane & 15, jg = lane >> 4;
        const int sr = t >> 2, sc0 = (t & 3) * 16;

        if (t < 256) {
            f32x4 s[4];
            #pragma unroll
            for (int j = 0; j < 4; ++j) s[j] = (f32x4){0.f, 0.f, 0.f, 0.f};
            for (int b = 0; b < 32; ++b) {
                const float* gbp = ws + WS_G + (size_t)b * 4096 + sr * 64 + sc0;
                #pragma unroll
                for (int j = 0; j < 4; ++j) s[j] += *(const f32x4*)(gbp + 4 * j);
            }
            s16x8 h8[2];
            #pragma unroll
            for (int q = 0; q < 2; ++q)
                #pragma unroll
                for (int j = 0; j < 8; ++j)
                    h8[q][j] = (short)bf16_rne_s(s[q * 2 + (j >> 2)][j & 3] * BN_INV);
            *(s16x8*)(&OPH0[sr * 72 + sc0])     = h8[0];
            *(s16x8*)(&OPH0[sr * 72 + sc0 + 8]) = h8[1];
            #pragma unroll
            for (int mtx = 0; mtx < 2; ++mtx) {
                const float* src = (mtx == 0 ? Wq : Wq2) + sr * 64 + sc0;
                float* F = (mtx == 0) ? F1 : F2;
                s16x8 g8[2];
                #pragma unroll
                for (int q = 0; q < 2; ++q) {
                    f32x4 a = *(const f32x4*)(src + q * 8);
                    f32x4 b = *(const f32x4*)(src + q * 8 + 4);
                    #pragma unroll
                    for (int j = 0; j < 8; ++j) {
                        float v = (j < 4) ? a[j] : b[j - 4];
                        F[sr * 65 + sc0 + q * 8 + j] = v;
                        g8[q][j] = (short)bf16_rne_s(v);
                    }
                }
                unsigned short* H = (mtx == 0) ? OPH1 : OPH2;
                *(s16x8*)(&H[sr * 72 + sc0])     = g8[0];
                *(s16x8*)(&H[sr * 72 + sc0 + 8]) = g8[1];
            }
        }
        if (t < 64) {
            float sm = 0.f;
            for (int b = 0; b < 32; ++b) sm += ws[WS_RB + b * 64 + t];
            mS[t] = sm * BN_INV;
            rl[t] = ws[WS_RB + bb * 64 + t];
            sbv[t] = bsr[t];
        }
        __syncthreads();

        auto mm64 = [&](const unsigned short* AH, const unsigned short* BH, f32x4 acc[4]) {
            #pragma unroll
            for (int ks = 0; ks < 2; ++ks) {
                const int ko = ks * 32 + jg * 8;
                s16x8 ah = *(const s16x8*)(AH + (16 * w + cl) * 72 + ko);
                #pragma unroll
                for (int bj = 0; bj < 4; ++bj) {
                    s16x8 bh = *(const s16x8*)(BH + (16 * bj + cl) * 72 + ko);
                    acc[bj] = __builtin_amdgcn_mfma_f32_16x16x32_bf16(ah, bh, acc[bj], 0, 0, 0);
                }
            }
        };

        // P1: Y = Wq·Gbar; quad = rowdot(Y,Wq); mu0 = Wq·m
        if (t < 256) {
            f32x4 acc[4];
            #pragma unroll
            for (int i = 0; i < 4; ++i) acc[i] = (f32x4){0.f, 0.f, 0.f, 0.f};
            mm64(OPH1, OPH0, acc);
            float s[4] = {0.f, 0.f, 0.f, 0.f};
            #pragma unroll
            for (int j = 0; j < 4; ++j) {
                const int row = 16 * w + jg * 4 + j;
                #pragma unroll
                for (int bj = 0; bj < 4; ++bj) s[j] += acc[bj][j] * F1[row * 65 + 16 * bj + cl];
            }
            #pragma unroll
            for (int m = 1; m <= 8; m <<= 1)
                #pragma unroll
                for (int j = 0; j < 4; ++j) s[j] += __shfl_xor(s[j], m);
            if (cl == 0) {
                #pragma unroll
                for (int j = 0; j < 4; ++j) quadS[16 * w + jg * 4 + j] = s[j];
            }
            if (t < 64) {
                float s2 = 0.f;
                for (int c = 0; c < 64; ++c) s2 += F1[t * 65 + c] * mS[c];
                muS[t] = s2;
            }
        }
        __syncthreads();

        // P2: D, abv; OPH0 := (D∘Wq)^T; avs = Wq2·abv + bq2
        if (t < 64) {
            const float var = quadS[t] - muS[t] * muS[t];
            const float D = gamma[t] * rsqrtf(var + 1e-5f);
            DSv[t] = D;
            abv[t] = beta[t] - D * muS[t];
        }
        __syncthreads();
        if (t < 256) {
            s16x8 h8[2];
            #pragma unroll
            for (int q = 0; q < 2; ++q)
                #pragma unroll
                for (int j = 0; j < 8; ++j) {
                    const int c = sc0 + q * 8 + j;
                    h8[q][j] = (short)bf16_rne_s(DSv[c] * F1[c * 65 + sr]);
                }
            *(s16x8*)(&OPH0[sr * 72 + sc0])     = h8[0];
            *(s16x8*)(&OPH0[sr * 72 + sc0 + 8]) = h8[1];
            if (t < 64) {
                float s = 0.f;
                for (int k = 0; k < 64; ++k) s += F2[t * 65 + k] * abv[k];
                avs[t] = s + bq2[t];
            }
        }
        __syncthreads();

        // P3: A = Wq2·(DWq); u = A·r; OPH1 := A
        if (t < 256) {
            f32x4 acc[4];
            #pragma unroll
            for (int i = 0; i < 4; ++i) acc[i] = (f32x4){0.f, 0.f, 0.f, 0.f};
            mm64(OPH2, OPH0, acc);
            float s[4] = {0.f, 0.f, 0.f, 0.f};
            #pragma unroll
            for (int bj = 0; bj < 4; ++bj) {
                const float cv = rl[16 * bj + cl];
                #pragma unroll
                for (int j = 0; j < 4; ++j) s[j] += acc[bj][j] * cv;
            }
            #pragma unroll
            for (int m = 1; m <= 8; m <<= 1)
                #pragma unroll
                for (int j = 0; j < 4; ++j) s[j] += __shfl_xor(s[j], m);
            if (cl == 0) {
                #pragma unroll
                for (int j = 0; j < 4; ++j) ul[16 * w + jg * 4 + j] = s[j];
            }
            #pragma unroll
            for (int bj = 0; bj < 4; ++bj)
                #pragma unroll
                for (int j = 0; j < 4; ++j) {
                    const int row = 16 * w + jg * 4 + j, col = 16 * bj + cl;
                    OPH1[row * 72 + col] = (unsigned short)bf16_rne_s(acc[bj][j]);
                }
        }
        __syncthreads();

        // P4: OPH0 := G_b; OPH2 := Wsr (+F1 f32)
        if (t < 256) {
            const float* gbp = ws + WS_G + (size_t)bb * 4096 + sr * 64 + sc0;
            s16x8 h8[2];
            #pragma unroll
            for (int q = 0; q < 2; ++q) {
                f32x4 a = *(const f32x4*)(gbp + q * 8);
                f32x4 b = *(const f32x4*)(gbp + q * 8 + 4);
                #pragma unroll
                for (int j = 0; j < 8; ++j)
                    h8[q][j] = (short)bf16_rne_s((j < 4) ? a[j] : b[j - 4]);
            }
            *(s16x8*)(&OPH0[sr * 72 + sc0])     = h8[0];
            *(s16x8*)(&OPH0[sr * 72 + sc0 + 8]) = h8[1];
            const float* ssrc = Wsr + sr * 64 + sc0;
            #pragma unroll
            for (int q = 0; q < 2; ++q) {
                f32x4 a = *(const f32x4*)(ssrc + q * 8);
                f32x4 b = *(const f32x4*)(ssrc + q * 8 + 4);
                #pragma unroll
                for (int j = 0; j < 8; ++j) {
                    float v = (j < 4) ? a[j] : b[j - 4];
                    F1[sr * 65 + sc0 + q * 8 + j] = v;
                    h8[q][j] = (short)bf16_rne_s(v);
                }
            }
            *(s16x8*)(&OPH2[sr * 72 + sc0])     = h8[0];
            *(s16x8*)(&OPH2[sr * 72 + sc0 + 8]) = h8[1];
        }
        __syncthreads();

        // P5: pls = Wsr·r + N·bsr; T = A·G_b (regs); OPH0 := T
        f32x4 accT[4];
        if (t < 256) {
            #pragma unroll
            for (int i = 0; i < 4; ++i) accT[i] = (f32x4){0.f, 0.f, 0.f, 0.f};
            if (t < 64) {
                float s = 0.f;
                for (int k = 0; k < 64; ++k) s += F1[t * 65 + k] * rl[k];
                pls[t] = s + 16384.f * sbv[t];
            }
            mm64(OPH1, OPH0, accT);
        }
        __syncthreads();
        if (t < 256) {
            #pragma unroll
            for (int bj = 0; bj < 4; ++bj)
                #pragma unroll
                for (int j = 0; j < 4; ++j) {
                    const int row = 16 * w + jg * 4 + j, col = 16 * bj + cl;
                    OPH0[row * 72 + col] = (unsigned short)bf16_rne_s(accT[bj][j]);
                }
        }
        __syncthreads();

        // P6: R = T·S^T + rank1; rowmax
        if (t < 256) {
            f32x4 acc[4];
            #pragma unroll
            for (int i = 0; i < 4; ++i) acc[i] = (f32x4){0.f, 0.f, 0.f, 0.f};
            mm64(OPH0, OPH2, acc);
            float mx[4] = {-3.4e38f, -3.4e38f, -3.4e38f, -3.4e38f};
            #pragma unroll
            for (int j = 0; j < 4; ++j) {
                const int row = 16 * w + jg * 4 + j;
                const float ur = ul[row], ar = avs[row];
                #pragma unroll
                for (int bj = 0; bj < 4; ++bj) {
                    const int col = 16 * bj + cl;
                    const float v = acc[bj][j] + ur * sbv[col] + ar * pls[col];
                    mx[j] = fmaxf(mx[j], v);
                }
            }
            #pragma unroll
            for (int m = 1; m <= 8; m <<= 1)
                #pragma unroll
                for (int j = 0; j < 4; ++j) mx[j] = fmaxf(mx[j], __shfl_xor(mx[j], m));
            if (cl == 0) {
                #pragma unroll
                for (int j = 0; j < 4; ++j) aml[16 * w + jg * 4 + j] = mx[j];
            }
        }
        __syncthreads();

        // P7: w_b = Wc·aml
        if (t < 64) {
            float s = 0.f;
            for (int c = 0; c < 64; ++c) s += Wc[t * 64 + c] * aml[c];
            ws[WS_W + bb * 64 + t] = s;
        }
    }
    __threadfence();
    grid.sync();

    // ================= Phase D: out = w ⊗ v =================
    {
        float* wls = (float*)smem;
        const int b = blockIdx.x >> 3, ch8 = blockIdx.x & 7;
        if (t < 64) wls[t] = ws[WS_W + b * 64 + t];
        __syncthreads();
        const size_t col = (size_t)ch8 * 2048 + (size_t)t * 4;
        const f32x4 v4 = *(const f32x4*)(ws + WS_V + (size_t)b * N_ + col);
        float* ob = out + (size_t)b * C_ * N_ + col;
        #pragma unroll
        for (int o = 0; o < 64; ++o) {
            __builtin_nontemporal_store(v4 * wls[o], (f32x4*)(ob + (size_t)o * N_));
        }
    }
}

// ===================== Fallback path (R7, proven) =====================
__global__ __launch_bounds__(512, 2) void k1(const float* __restrict__ x, float* __restrict__ ws) {
    __shared__ __align__(16) float rawb[4][10 * 256];
    __shared__ float rws[8][64];
    const int t = threadIdx.x, wv = t >> 6, lane = t & 63;
    const int b = blockIdx.x >> 4, ch = blockIdx.x & 15;
    const int kg = lane >> 4, cl = lane & 15;
    const float* xb = x + ((size_t)b * C_ + cl) * N_ + ch * 1024 + kg * 8;

    f32x4 accP1[10];
    #pragma unroll
    for (int i = 0; i < 10; ++i) accP1[i] = (f32x4){0.f, 0.f, 0.f, 0.f};
    f32x4 rs = {0.f, 0.f, 0.f, 0.f};

    f32x4 cA[4], cB[4], nA[4], nB[4];
    #pragma unroll
    for (int g = 0; g < 4; ++g) {
        cA[g] = *(const f32x4*)(xb + (size_t)g * (16 * N_) + wv * 32);
        cB[g] = *(const f32x4*)(xb + (size_t)g * (16 * N_) + wv * 32 + 4);
    }
    for (int w = 0; w < 4; ++w) {
        if (w < 3) {
            const int noff = (8 * (w + 1) + wv) * 32;
            #pragma unroll
            for (int g = 0; g < 4; ++g) {
                nA[g] = *(const f32x4*)(xb + (size_t)g * (16 * N_) + noff);
                nB[g] = *(const f32x4*)(xb + (size_t)g * (16 * N_) + noff + 4);
            }
        }
        s16x8 hi[4];
        #pragma unroll
        for (int g = 0; g < 4; ++g) cvt8hi(cA[g], cB[g], hi[g]);
        f32x4 s0 = cA[0] + cA[1] + cA[2] + cA[3];
        f32x4 s1 = cB[0] + cB[1] + cB[2] + cB[3];
        #pragma unroll
        for (int m = 1; m <= 8; m <<= 1) {
            #pragma unroll
            for (int j = 0; j < 4; ++j) {
                s0[j] += __shfl_xor(s0[j], m);
                s1[j] += __shfl_xor(s1[j], m);
            }
        }
        if (cl == 0) {
            float* vp = ws + WS_V + (size_t)b * N_ + ch * 1024 + (8 * w + wv) * 32 + kg * 8;
            *(f32x4*)vp       = s0 * 0.015625f;
            *(f32x4*)(vp + 4) = s1 * 0.015625f;
        }
        #pragma unroll
        for (int g = 0; g < 4; ++g)
            rs[g] += cA[g][0] + cA[g][1] + cA[g][2] + cA[g][3]
                   + cB[g][0] + cB[g][1] + cB[g][2] + cB[g][3];
        #pragma unroll
        for (int i = 0; i < 10; ++i)
            accP1[i] = __builtin_amdgcn_mfma_f32_16x16x32_bf16(hi[P1I[i]], hi[P1J[i]], accP1[i], 0, 0, 0);
        #pragma unroll
        for (int g = 0; g < 4; ++g) { cA[g] = nA[g]; cB[g] = nB[g]; }
    }
    #pragma unroll
    for (int g = 0; g < 4; ++g) {
        rs[g] += __shfl_xor(rs[g], 16);
        rs[g] += __shfl_xor(rs[g], 32);
    }
    if (lane < 16) {
        #pragma unroll
        for (int g = 0; g < 4; ++g) rws[wv][g * 16 + lane] = rs[g];
    }
    if (wv < 4) {
        float* dst = rawb[wv];
        #pragma unroll
        for (int i = 0; i < 10; ++i) *(f32x4*)(dst + i * 256 + lane * 4) = accP1[i];
    }
    __syncthreads();
    if (wv >= 4) {
        float* dst = rawb[wv - 4];
        #pragma unroll
        for (int i = 0; i < 10; ++i) {
            f32x4 o = *(f32x4*)(dst + i * 256 + lane * 4);
            *(f32x4*)(dst + i * 256 + lane * 4) = o + accP1[i];
        }
    }
    __syncthreads();
    if (t < 64) {
        float s = 0.f;
        #pragma unroll
        for (int g = 0; g < 8; ++g) s += rws[g][t];
        ws[WS_RPART + (size_t)blockIdx.x * 64 + t] = s;
    }
    float* gp = ws + WS_GPART + (size_t)blockIdx.x * 4096;
    for (int e = t; e < 4096; e += 512) {
        const int r = e >> 6, c = e & 63;
        const int bi = r >> 4, bj = c >> 4, rr = r & 15, cc = c & 15;
        const int i1 = P1AT[bi][bj] * 256;
        const int o1 = (bi <= bj) ? (((rr >> 2) * 16 + cc) * 4 + (rr & 3))
                                  : (((cc >> 2) * 16 + rr) * 4 + (cc & 3));
        gp[e] = rawb[0][i1 + o1] + rawb[1][i1 + o1] + rawb[2][i1 + o1] + rawb[3][i1 + o1];
    }
}

__global__ __launch_bounds__(256) void k2a(float* __restrict__ ws) {
    const int b = blockIdx.x >> 3, sl = blockIdx.x & 7, t = threadIdx.x;
    #pragma unroll
    for (int h = 0; h < 2; ++h) {
        const int e = sl * 512 + h * 256 + t;
        float s = 0.f;
        for (int chn = 0; chn < 16; ++chn) s += ws[WS_GPART + ((size_t)(b * 16 + chn)) * 4096 + e];
        ws[WS_G + (size_t)b * 4096 + e] = s;
    }
    if (sl == 0 && t < 64) {
        float s = 0.f;
        for (int chn = 0; chn < 16; ++chn) s += ws[WS_RPART + (size_t)(b * 16 + chn) * 64 + t];
        ws[WS_RB + b * 64 + t] = s;
    }
}

__global__ __launch_bounds__(256) void k2b(const float* __restrict__ Wq, const float* __restrict__ gamma,
                                           const float* __restrict__ beta, const float* __restrict__ Wq2,
                                           const float* __restrict__ bq2, const float* __restrict__ Wsr,
                                           const float* __restrict__ bsr, const float* __restrict__ Wc,
                                           float* __restrict__ ws) {
    __shared__ __align__(16) unsigned short OPH[3][64 * 72];
    __shared__ float F1[64 * 65], F2[64 * 65];
    __shared__ float mS[64], muS[64], DS[64], abv[64], quadS[64];
    __shared__ float rl[64], ul[64], avs[64], sbv[64], pls[64], aml[64];
    const int bb = blockIdx.x, t = threadIdx.x;
    const int w = t >> 6, lane = t & 63, cl = lane & 15, jg = lane >> 4;
    const int sr = t >> 2, sc0 = (t & 3) * 16;
    {
        f32x4 s[4];
        #pragma unroll
        for (int j = 0; j < 4; ++j) s[j] = (f32x4){0.f, 0.f, 0.f, 0.f};
        for (int b = 0; b < 32; ++b) {
            const float* gbp = ws + WS_G + (size_t)b * 4096 + sr * 64 + sc0;
            #pragma unroll
            for (int j = 0; j < 4; ++j) s[j] += *(const f32x4*)(gbp + 4 * j);
        }
        s16x8 h8[2];
        #pragma unroll
        for (int q = 0; q < 2; ++q)
            #pragma unroll
            for (int j = 0; j < 8; ++j)
                h8[q][j] = (short)bf16_rne_s(s[q * 2 + (j >> 2)][j & 3] * BN_INV);
        *(s16x8*)(&OPH[0][sr * 72 + sc0])     = h8[0];
        *(s16x8*)(&OPH[0][sr * 72 + sc0 + 8]) = h8[1];
    }
    #pragma unroll
    for (int mtx = 0; mtx < 2; ++mtx) {
        const float* src = (mtx == 0 ? Wq : Wq2) + sr * 64 + sc0;
        float* F = (mtx == 0) ? F1 : F2;
        s16x8 h8[2];
        #pragma unroll
        for (int q = 0; q < 2; ++q) {
            f32x4 a = *(const f32x4*)(src + q * 8);
            f32x4 b = *(const f32x4*)(src + q * 8 + 4);
            #pragma unroll
            for (int j = 0; j < 8; ++j) {
                float v = (j < 4) ? a[j] : b[j - 4];
                F[sr * 65 + sc0 + q * 8 + j] = v;
                h8[q][j] = (short)bf16_rne_s(v);
            }
        }
        unsigned short* H = OPH[1 + mtx];
        *(s16x8*)(&H[sr * 72 + sc0])     = h8[0];
        *(s16x8*)(&H[sr * 72 + sc0 + 8]) = h8[1];
    }
    if (t < 64) {
        float sm = 0.f;
        for (int b = 0; b < 32; ++b) sm += ws[WS_RB + b * 64 + t];
        mS[t] = sm * BN_INV;
        rl[t] = ws[WS_RB + bb * 64 + t];
        sbv[t] = bsr[t];
    }
    __syncthreads();
    auto mm64 = [&](const unsigned short* AH, const unsigned short* BH, f32x4 acc[4]) {
        #pragma unroll
        for (int ks = 0; ks < 2; ++ks) {
            const int ko = ks * 32 + jg * 8;
            s16x8 ah = *(const s16x8*)(AH + (16 * w + cl) * 72 + ko);
            #pragma unroll
            for (int bj = 0; bj < 4; ++bj) {
                s16x8 bh = *(const s16x8*)(BH + (16 * bj + cl) * 72 + ko);
                acc[bj] = __builtin_amdgcn_mfma_f32_16x16x32_bf16(ah, bh, acc[bj], 0, 0, 0);
            }
        }
    };
    {
        f32x4 acc[4];
        #pragma unroll
        for (int i = 0; i < 4; ++i) acc[i] = (f32x4){0.f, 0.f, 0.f, 0.f};
        mm64(OPH[1], OPH[0], acc);
        float s[4] = {0.f, 0.f, 0.f, 0.f};
        #pragma unroll
        for (int j = 0; j < 4; ++j) {
            const int row = 16 * w + jg * 4 + j;
            #pragma unroll
            for (int bj = 0; bj < 4; ++bj) s[j] += acc[bj][j] * F1[row * 65 + 16 * bj + cl];
        }
        #pragma unroll
        for (int m = 1; m <= 8; m <<= 1)
            #pragma unroll
            for (int j = 0; j < 4; ++j) s[j] += __shfl_xor(s[j], m);
        if (cl == 0) {
            #pragma unroll
            for (int j = 0; j < 4; ++j) quadS[16 * w + jg * 4 + j] = s[j];
        }
        if (t < 64) {
            float s2 = 0.f;
            for (int c = 0; c < 64; ++c) s2 += F1[t * 65 + c] * mS[c];
            muS[t] = s2;
        }
    }
    __syncthreads();
    if (t < 64) {
        const float var = quadS[t] - muS[t] * muS[t];
        const float D = gamma[t] * rsqrtf(var + 1e-5f);
        DS[t] = D;
        abv[t] = beta[t] - D * muS[t];
    }
    __syncthreads();
    {
        s16x8 h8[2];
        #pragma unroll
        for (int q = 0; q < 2; ++q)
            #pragma unroll
            for (int j = 0; j < 8; ++j) {
                const int c = sc0 + q * 8 + j;
                h8[q][j] = (short)bf16_rne_s(DS[c] * F1[c * 65 + sr]);
            }
        *(s16x8*)(&OPH[0][sr * 72 + sc0])     = h8[0];
        *(s16x8*)(&OPH[0][sr * 72 + sc0 + 8]) = h8[1];
    }
    if (t < 64) {
        float s = 0.f;
        for (int k = 0; k < 64; ++k) s += F2[t * 65 + k] * abv[k];
        avs[t] = s + bq2[t];
    }
    __syncthreads();
    {
        f32x4 acc[4];
        #pragma unroll
        for (int i = 0; i < 4; ++i) acc[i] = (f32x4){0.f, 0.f, 0.f, 0.f};
        mm64(OPH[2], OPH[0], acc);
        float s[4] = {0.f, 0.f, 0.f, 0.f};
        #pragma unroll
        for (int bj = 0; bj < 4; ++bj) {
            const float cv = rl[16 * bj + cl];
            #pragma unroll
            for (int j = 0; j < 4; ++j) s[j] += acc[bj][j] * cv;
        }
        #pragma unroll
        for (int m = 1; m <= 8; m <<= 1)
            #pragma unroll
            for (int j = 0; j < 4; ++j) s[j] += __shfl_xor(s[j], m);
        if (cl == 0) {
            #pragma unroll
            for (int j = 0; j < 4; ++j) ul[16 * w + jg * 4 + j] = s[j];
        }
        #pragma unroll
        for (int bj = 0; bj < 4; ++bj)
            #pragma unroll
            for (int j = 0; j < 4; ++j) {
                const int row = 16 * w + jg * 4 + j, col = 16 * bj + cl;
                OPH[1][row * 72 + col] = (unsigned short)bf16_rne_s(acc[bj][j]);
            }
    }
    __syncthreads();
    {
        const float* gbp = ws + WS_G + (size_t)bb * 4096 + sr * 64 + sc0;
        s16x8 h8[2];
        #pragma unroll
        for (int q = 0; q < 2; ++q) {
            f32x4 a = *(const f32x4*)(gbp + q * 8);
            f32x4 b = *(const f32x4*)(gbp + q * 8 + 4);
            #pragma unroll
            for (int j = 0; j < 8; ++j)
                h8[q][j] = (short)bf16_rne_s((j < 4) ? a[j] : b[j - 4]);
        }
        *(s16x8*)(&OPH[0][sr * 72 + sc0])     = h8[0];
        *(s16x8*)(&OPH[0][sr * 72 + sc0 + 8]) = h8[1];
        const float* ssrc = Wsr + sr * 64 + sc0;
        #pragma unroll
        for (int q = 0; q < 2; ++q) {
            f32x4 a = *(const f32x4*)(ssrc + q * 8);
            f32x4 b = *(const f32x4*)(ssrc + q * 8 + 4);
            #pragma unroll
            for (int j = 0; j < 8; ++j) {
                float v = (j < 4) ? a[j] : b[j - 4];
                F1[sr * 65 + sc0 + q * 8 + j] = v;
                h8[q][j] = (short)bf16_rne_s(v);
            }
        }
        *(s16x8*)(&OPH[2][sr * 72 + sc0])     = h8[0];
        *(s16x8*)(&OPH[2][sr * 72 + sc0 + 8]) = h8[1];
    }
    __syncthreads();
    f32x4 accT[4];
    #pragma unroll
    for (int i = 0; i < 4; ++i) accT[i] = (f32x4){0.f, 0.f, 0.f, 0.f};
    if (t < 64) {
        float s = 0.f;
        for (int k = 0; k < 64; ++k) s += F1[t * 65 + k] * rl[k];
        pls[t] = s + 16384.f * sbv[t];
    }
    mm64(OPH[1], OPH[0], accT);
    __syncthreads();
    #pragma unroll
    for (int bj = 0; bj < 4; ++bj)
        #pragma unroll
        for (int j = 0; j < 4; ++j) {
            const int row = 16 * w + jg * 4 + j, col = 16 * bj + cl;
            OPH[0][row * 72 + col] = (unsigned short)bf16_rne_s(accT[bj][j]);
        }
    __syncthreads();
    {
        f32x4 acc[4];
        #pragma unroll
        for (int i = 0; i < 4; ++i) acc[i] = (f32x4){0.f, 0.f, 0.f, 0.f};
        mm64(OPH[0], OPH[2], acc);
        float mx[4] = {-3.4e38f, -3.4e38f, -3.4e38f, -3.4e38f};
        #pragma unroll
        for (int j = 0; j < 4; ++j) {
            const int row = 16 * w + jg * 4 + j;
            const float ur = ul[row], ar = avs[row];
            #pragma unroll
            for (int bj = 0; bj < 4; ++bj) {
                const int col = 16 * bj + cl;
                const float v = acc[bj][j] + ur * sbv[col] + ar * pls[col];
                mx[j] = fmaxf(mx[j], v);
            }
        }
        #pragma unroll
        for (int m = 1; m <= 8; m <<= 1)
            #pragma unroll
            for (int j = 0; j < 4; ++j) mx[j] = fmaxf(mx[j], __shfl_xor(mx[j], m));
        if (cl == 0) {
            #pragma unroll
            for (int j = 0; j < 4; ++j) aml[16 * w + jg * 4 + j] = mx[j];
        }
    }
    __syncthreads();
    if (t < 64) {
        float s = 0.f;
        for (int c = 0; c < 64; ++c) s += Wc[t * 64 + c] * aml[c];
        ws[WS_W + bb * 64 + t] = s;
    }
}

__global__ __launch_bounds__(256) void k3(const float* __restrict__ ws, float* __restrict__ out) {
    const int blk = blockIdx.x;
    const int b = blk >> 6, seg = blk & 63;
    const int r0 = (seg >> 4) * 16, chk = seg & 15;
    __shared__ float wls[16];
    const int t = threadIdx.x;
    if (t < 16) wls[t] = ws[WS_W + b * 64 + r0 + t];
    __syncthreads();
    const size_t nb = (size_t)chk * 1024 + 4 * t;
    const f32x4 v4 = *(const f32x4*)(ws + WS_V + (size_t)b * N_ + nb);
    float* ob = out + ((size_t)b * C_ + r0) * N_ + nb;
    #pragma unroll
    for (int o = 0; o < 16; ++o) {
        __builtin_nontemporal_store(v4 * wls[o], (f32x4*)(ob + (size_t)o * N_));
    }
}

extern "C" void kernel_launch(void* const* d_in, const int* in_sizes, int n_in,
                              void* d_out, int out_size, void* d_ws, size_t ws_size,
                              hipStream_t stream) {
    const float* x     = (const float*)d_in[0];
    const float* Wq    = (const float*)d_in[1];
    const float* gamma = (const float*)d_in[3];
    const float* beta  = (const float*)d_in[4];
    const float* Wq2   = (const float*)d_in[5];
    const float* bq2   = (const float*)d_in[6];
    const float* Wsr   = (const float*)d_in[7];
    const float* bsr   = (const float*)d_in[8];
    const float* Wc    = (const float*)d_in[9];
    float* ws  = (float*)d_ws;
    float* out = (float*)d_out;

    void* args[] = {(void*)&x, (void*)&Wq, (void*)&gamma, (void*)&beta, (void*)&Wq2,
                    (void*)&bq2, (void*)&Wsr, (void*)&bsr, (void*)&Wc, (void*)&ws, (void*)&out};
    hipError_t err = hipLaunchCooperativeKernel((void*)mega, dim3(256), dim3(512), args, 0, stream);
    if (err != hipSuccess) {
        (void)hipGetLastError();   // clear error state; fall back to proven 4-kernel path
        hipLaunchKernelGGL(k1,  dim3(512),  dim3(512), 0, stream, x, ws);
        hipLaunchKernelGGL(k2a, dim3(256),  dim3(256), 0, stream, ws);
        hipLaunchKernelGGL(k2b, dim3(32),   dim3(256), 0, stream,
                           Wq, gamma, beta, Wq2, bq2, Wsr, bsr, Wc, ws);
        hipLaunchKernelGGL(k3,  dim3(2048), dim3(256), 0, stream, ws, out);
    }
}

// Round 10
// 116.591 us; speedup vs baseline: 2.5228x; 2.5228x over previous
//
#include <hip/hip_runtime.h>
#include <hip/hip_bf16.h>

// Problem constants (B,C,N fixed by the reference)
#define B_ 32
#define C_ 64
#define N_ 16384
constexpr float BN_INV = 1.0f / (32.0f * 16384.0f);   // 1/(B*N)

typedef float f32x4 __attribute__((ext_vector_type(4)));
typedef short s16x8 __attribute__((ext_vector_type(8)));

// ---- workspace layout (float offsets) ----
constexpr size_t WS_GPART = 0;                               // [512][4096] per-(b,chunk) Gram partials
constexpr size_t WS_RPART = WS_GPART + (size_t)512 * 4096;   // [512][64]   rowsum partials
constexpr size_t WS_G     = WS_RPART + (size_t)512 * 64;     // [32][4096]  per-batch Gram
constexpr size_t WS_RB    = WS_G + (size_t)32 * 4096;        // [32][64]    per-batch rowsums
constexpr size_t WS_V     = WS_RB + (size_t)32 * 64;         // [32][16384] channel means
constexpr size_t WS_W     = WS_V + (size_t)32 * N_;          // [32][64]    w_b = Wc @ attnmax

__device__ constexpr int P1I[10] = {0,0,0,0,1,1,1,2,2,3};
__device__ constexpr int P1J[10] = {0,1,2,3,1,2,3,2,3,3};
__device__ constexpr int P1AT[4][4] = {{0,1,2,3},{1,4,5,6},{2,5,7,8},{3,6,8,9}};

__device__ __forceinline__ unsigned short bf16_rne_s(float f) {
    unsigned u = __float_as_uint(f);
    unsigned r = u + 0x7FFFu + ((u >> 16) & 1u);
    return (unsigned short)(r >> 16);
}
__device__ __forceinline__ void cvt8hi(const f32x4& a, const f32x4& b, s16x8& hi) {
    float f[8] = {a[0], a[1], a[2], a[3], b[0], b[1], b[2], b[3]};
    #pragma unroll
    for (int j = 0; j < 8; ++j) hi[j] = (short)bf16_rne_s(f[j]);
}

// ============ K1: barrier-free per-wave Gram (hi bf16 MFMA) + v + rowsums ============
// 512 blocks x 256 threads (4 waves), __launch_bounds__(256,5) -> VGPR<=102,
// 5 blocks/CU = 20 waves/CU (vs 16 at the old 512-thread config) for latency hiding.
// Each wave owns 8 windows of 32 columns; lane layout == MFMA fragment layout.
__global__ __launch_bounds__(256, 5) void k1(const float* __restrict__ x, float* __restrict__ ws) {
    __shared__ __align__(16) float rawb[2][10 * 256];   // 20 KB reduction tree
    __shared__ float rws[4][64];
    const int t = threadIdx.x, wv = t >> 6, lane = t & 63;
    const int b = blockIdx.x >> 4, ch = blockIdx.x & 15;
    const int kg = lane >> 4, cl = lane & 15;
    const float* xb = x + ((size_t)b * C_ + cl) * N_ + ch * 1024 + kg * 8;

    f32x4 accP1[10];
    #pragma unroll
    for (int i = 0; i < 10; ++i) accP1[i] = (f32x4){0.f, 0.f, 0.f, 0.f};
    f32x4 rs = {0.f, 0.f, 0.f, 0.f};

    f32x4 cA[4], cB[4], nA[4], nB[4];
    #pragma unroll
    for (int g = 0; g < 4; ++g) {
        cA[g] = *(const f32x4*)(xb + (size_t)g * (16 * N_) + wv * 32);
        cB[g] = *(const f32x4*)(xb + (size_t)g * (16 * N_) + wv * 32 + 4);
    }

    for (int w = 0; w < 8; ++w) {
        if (w < 7) {   // prefetch next window before any compute
            const int noff = (4 * (w + 1) + wv) * 32;
            #pragma unroll
            for (int g = 0; g < 4; ++g) {
                nA[g] = *(const f32x4*)(xb + (size_t)g * (16 * N_) + noff);
                nB[g] = *(const f32x4*)(xb + (size_t)g * (16 * N_) + noff + 4);
            }
        }
        s16x8 hi[4];
        #pragma unroll
        for (int g = 0; g < 4; ++g) cvt8hi(cA[g], cB[g], hi[g]);

        // v: sum over 64 channels = local over g + 16-lane butterfly
        f32x4 s0 = cA[0] + cA[1] + cA[2] + cA[3];
        f32x4 s1 = cB[0] + cB[1] + cB[2] + cB[3];
        #pragma unroll
        for (int m = 1; m <= 8; m <<= 1) {
            #pragma unroll
            for (int j = 0; j < 4; ++j) {
                s0[j] += __shfl_xor(s0[j], m);
                s1[j] += __shfl_xor(s1[j], m);
            }
        }
        if (cl == 0) {
            float* vp = ws + WS_V + (size_t)b * N_ + ch * 1024 + (4 * w + wv) * 32 + kg * 8;
            *(f32x4*)vp       = s0 * 0.015625f;
            *(f32x4*)(vp + 4) = s1 * 0.015625f;
        }
        // rowsums (lane-local)
        #pragma unroll
        for (int g = 0; g < 4; ++g)
            rs[g] += cA[g][0] + cA[g][1] + cA[g][2] + cA[g][3]
                   + cB[g][0] + cB[g][1] + cB[g][2] + cB[g][3];

        // Gram: P1 = Hi Hi^T (10 upper blocks)
        #pragma unroll
        for (int i = 0; i < 10; ++i)
            accP1[i] = __builtin_amdgcn_mfma_f32_16x16x32_bf16(hi[P1I[i]], hi[P1J[i]], accP1[i], 0, 0, 0);

        #pragma unroll
        for (int g = 0; g < 4; ++g) { cA[g] = nA[g]; cB[g] = nB[g]; }
    }

    // rowsum: fold k-groups (lanes ^16, ^32 share channel residue)
    #pragma unroll
    for (int g = 0; g < 4; ++g) {
        rs[g] += __shfl_xor(rs[g], 16);
        rs[g] += __shfl_xor(rs[g], 32);
    }
    if (lane < 16) {
        #pragma unroll
        for (int g = 0; g < 4; ++g) rws[wv][g * 16 + lane] = rs[g];
    }

    // G reduction tree: waves 0,1 write raw; waves 2,3 add; all gather+symmetrize
    if (wv < 2) {
        float* dst = rawb[wv];
        #pragma unroll
        for (int i = 0; i < 10; ++i) *(f32x4*)(dst + i * 256 + lane * 4) = accP1[i];
    }
    __syncthreads();
    if (wv >= 2) {
        float* dst = rawb[wv - 2];
        #pragma unroll
        for (int i = 0; i < 10; ++i) {
            f32x4 o = *(f32x4*)(dst + i * 256 + lane * 4);
            *(f32x4*)(dst + i * 256 + lane * 4) = o + accP1[i];
        }
    }
    __syncthreads();
    if (t < 64) {
        ws[WS_RPART + (size_t)blockIdx.x * 64 + t] =
            rws[0][t] + rws[1][t] + rws[2][t] + rws[3][t];
    }
    float* gp = ws + WS_GPART + (size_t)blockIdx.x * 4096;
    for (int e = t; e < 4096; e += 256) {
        const int r = e >> 6, c = e & 63;
        const int bi = r >> 4, bj = c >> 4, rr = r & 15, cc = c & 15;
        const int i1 = P1AT[bi][bj] * 256;
        const int o1 = (bi <= bj) ? (((rr >> 2) * 16 + cc) * 4 + (rr & 3))
                                  : (((cc >> 2) * 16 + rr) * 4 + (cc & 3));
        gp[e] = rawb[0][i1 + o1] + rawb[1][i1 + o1];
    }
}

// ============ K2a: reduce chunk partials -> per-batch G, r ============
__global__ __launch_bounds__(256) void k2a(float* __restrict__ ws) {
    const int b = blockIdx.x >> 3, sl = blockIdx.x & 7, t = threadIdx.x;
    #pragma unroll
    for (int h = 0; h < 2; ++h) {
        const int e = sl * 512 + h * 256 + t;
        float s = 0.f;
        for (int chn = 0; chn < 16; ++chn) s += ws[WS_GPART + ((size_t)(b * 16 + chn)) * 4096 + e];
        ws[WS_G + (size_t)b * 4096 + e] = s;
    }
    if (sl == 0 && t < 64) {
        float s = 0.f;
        for (int chn = 0; chn < 16; ++chn) s += ws[WS_RPART + (size_t)(b * 16 + chn) * 64 + t];
        ws[WS_RB + b * 64 + t] = s;
    }
}

// ============ K2b: MFMA-based C×C algebra (hh-only bf16), one block per batch ============
__global__ __launch_bounds__(256) void k2b(const float* __restrict__ Wq, const float* __restrict__ gamma,
                                           const float* __restrict__ beta, const float* __restrict__ Wq2,
                                           const float* __restrict__ bq2, const float* __restrict__ Wsr,
                                           const float* __restrict__ bsr, const float* __restrict__ Wc,
                                           float* __restrict__ ws) {
    __shared__ __align__(16) unsigned short OPH[3][64 * 72];   // bf16 operand slots (27.6 KB)
    __shared__ float F1[64 * 65], F2[64 * 65];
    __shared__ float mS[64], muS[64], DS[64], abv[64], quadS[64];
    __shared__ float rl[64], ul[64], avs[64], sbv[64], pls[64], aml[64];
    const int bb = blockIdx.x, t = threadIdx.x;
    const int w = t >> 6, lane = t & 63, cl = lane & 15, jg = lane >> 4;
    const int sr = t >> 2, sc0 = (t & 3) * 16;

    // ---- P0: stage Gbar->OP0, Wq->F1+OP1, Wq2->F2+OP2, vectors ----
    {
        f32x4 s[4];
        #pragma unroll
        for (int j = 0; j < 4; ++j) s[j] = (f32x4){0.f, 0.f, 0.f, 0.f};
        for (int b = 0; b < 32; ++b) {
            const float* gbp = ws + WS_G + (size_t)b * 4096 + sr * 64 + sc0;
            #pragma unroll
            for (int j = 0; j < 4; ++j) s[j] += *(const f32x4*)(gbp + 4 * j);
        }
        s16x8 h8[2];
        #pragma unroll
        for (int q = 0; q < 2; ++q)
            #pragma unroll
            for (int j = 0; j < 8; ++j)
                h8[q][j] = (short)bf16_rne_s(s[q * 2 + (j >> 2)][j & 3] * BN_INV);
        *(s16x8*)(&OPH[0][sr * 72 + sc0])     = h8[0];
        *(s16x8*)(&OPH[0][sr * 72 + sc0 + 8]) = h8[1];
    }
    #pragma unroll
    for (int mtx = 0; mtx < 2; ++mtx) {
        const float* src = (mtx == 0 ? Wq : Wq2) + sr * 64 + sc0;
        float* F = (mtx == 0) ? F1 : F2;
        s16x8 h8[2];
        #pragma unroll
        for (int q = 0; q < 2; ++q) {
            f32x4 a = *(const f32x4*)(src + q * 8);
            f32x4 b = *(const f32x4*)(src + q * 8 + 4);
            #pragma unroll
            for (int j = 0; j < 8; ++j) {
                float v = (j < 4) ? a[j] : b[j - 4];
                F[sr * 65 + sc0 + q * 8 + j] = v;
                h8[q][j] = (short)bf16_rne_s(v);
            }
        }
        unsigned short* H = OPH[1 + mtx];
        *(s16x8*)(&H[sr * 72 + sc0])     = h8[0];
        *(s16x8*)(&H[sr * 72 + sc0 + 8]) = h8[1];
    }
    if (t < 64) {
        float sm = 0.f;
        for (int b = 0; b < 32; ++b) sm += ws[WS_RB + b * 64 + t];
        mS[t] = sm * BN_INV;
        rl[t] = ws[WS_RB + bb * 64 + t];
        sbv[t] = bsr[t];
    }
    __syncthreads();

    auto mm64 = [&](const unsigned short* AH, const unsigned short* BH, f32x4 acc[4]) {
        #pragma unroll
        for (int ks = 0; ks < 2; ++ks) {
            const int ko = ks * 32 + jg * 8;
            s16x8 ah = *(const s16x8*)(AH + (16 * w + cl) * 72 + ko);
            #pragma unroll
            for (int bj = 0; bj < 4; ++bj) {
                s16x8 bh = *(const s16x8*)(BH + (16 * bj + cl) * 72 + ko);
                acc[bj] = __builtin_amdgcn_mfma_f32_16x16x32_bf16(ah, bh, acc[bj], 0, 0, 0);
            }
        }
    };
    // acc element (bj, j) sits at (row = 16w + jg*4 + j, col = 16bj + cl)

    // ---- P1: Y = Wq·Gbar; quad_o = rowdot(Y, Wq); mu0 = Wq·m ----
    {
        f32x4 acc[4];
        #pragma unroll
        for (int i = 0; i < 4; ++i) acc[i] = (f32x4){0.f, 0.f, 0.f, 0.f};
        mm64(OPH[1], OPH[0], acc);
        float s[4] = {0.f, 0.f, 0.f, 0.f};
        #pragma unroll
        for (int j = 0; j < 4; ++j) {
            const int row = 16 * w + jg * 4 + j;
            #pragma unroll
            for (int bj = 0; bj < 4; ++bj) s[j] += acc[bj][j] * F1[row * 65 + 16 * bj + cl];
        }
        #pragma unroll
        for (int m = 1; m <= 8; m <<= 1)
            #pragma unroll
            for (int j = 0; j < 4; ++j) s[j] += __shfl_xor(s[j], m);
        if (cl == 0) {
            #pragma unroll
            for (int j = 0; j < 4; ++j) quadS[16 * w + jg * 4 + j] = s[j];
        }
        if (t < 64) {
            float s2 = 0.f;
            for (int c = 0; c < 64; ++c) s2 += F1[t * 65 + c] * mS[c];
            muS[t] = s2;
        }
    }
    __syncthreads();

    // ---- P2: D, abv; OP0 := (D∘Wq)^T; avs = Wq2·abv + bq2 ----
    if (t < 64) {
        const float var = quadS[t] - muS[t] * muS[t];
        const float D = gamma[t] * rsqrtf(var + 1e-5f);
        DS[t] = D;
        abv[t] = beta[t] - D * muS[t];
    }
    __syncthreads();
    {
        s16x8 h8[2];
        #pragma unroll
        for (int q = 0; q < 2; ++q)
            #pragma unroll
            for (int j = 0; j < 8; ++j) {
                const int c = sc0 + q * 8 + j;
                h8[q][j] = (short)bf16_rne_s(DS[c] * F1[c * 65 + sr]);
            }
        *(s16x8*)(&OPH[0][sr * 72 + sc0])     = h8[0];
        *(s16x8*)(&OPH[0][sr * 72 + sc0 + 8]) = h8[1];
    }
    if (t < 64) {
        float s = 0.f;
        for (int k = 0; k < 64; ++k) s += F2[t * 65 + k] * abv[k];
        avs[t] = s + bq2[t];
    }
    __syncthreads();

    // ---- P3: A = Wq2·(DWq); u = A·r; OP1 := A ----
    {
        f32x4 acc[4];
        #pragma unroll
        for (int i = 0; i < 4; ++i) acc[i] = (f32x4){0.f, 0.f, 0.f, 0.f};
        mm64(OPH[2], OPH[0], acc);
        float s[4] = {0.f, 0.f, 0.f, 0.f};
        #pragma unroll
        for (int bj = 0; bj < 4; ++bj) {
            const float cv = rl[16 * bj + cl];
            #pragma unroll
            for (int j = 0; j < 4; ++j) s[j] += acc[bj][j] * cv;
        }
        #pragma unroll
        for (int m = 1; m <= 8; m <<= 1)
            #pragma unroll
            for (int j = 0; j < 4; ++j) s[j] += __shfl_xor(s[j], m);
        if (cl == 0) {
            #pragma unroll
            for (int j = 0; j < 4; ++j) ul[16 * w + jg * 4 + j] = s[j];
        }
        #pragma unroll
        for (int bj = 0; bj < 4; ++bj)
            #pragma unroll
            for (int j = 0; j < 4; ++j) {
                const int row = 16 * w + jg * 4 + j, col = 16 * bj + cl;
                OPH[1][row * 72 + col] = (unsigned short)bf16_rne_s(acc[bj][j]);
            }
    }
    __syncthreads();

    // ---- P4: OP0 := G_b rows; OP2 := Wsr rows (+F1 f32) ----
    {
        const float* gbp = ws + WS_G + (size_t)bb * 4096 + sr * 64 + sc0;
        s16x8 h8[2];
        #pragma unroll
        for (int q = 0; q < 2; ++q) {
            f32x4 a = *(const f32x4*)(gbp + q * 8);
            f32x4 b = *(const f32x4*)(gbp + q * 8 + 4);
            #pragma unroll
            for (int j = 0; j < 8; ++j)
                h8[q][j] = (short)bf16_rne_s((j < 4) ? a[j] : b[j - 4]);
        }
        *(s16x8*)(&OPH[0][sr * 72 + sc0])     = h8[0];
        *(s16x8*)(&OPH[0][sr * 72 + sc0 + 8]) = h8[1];
        const float* ssrc = Wsr + sr * 64 + sc0;
        #pragma unroll
        for (int q = 0; q < 2; ++q) {
            f32x4 a = *(const f32x4*)(ssrc + q * 8);
            f32x4 b = *(const f32x4*)(ssrc + q * 8 + 4);
            #pragma unroll
            for (int j = 0; j < 8; ++j) {
                float v = (j < 4) ? a[j] : b[j - 4];
                F1[sr * 65 + sc0 + q * 8 + j] = v;
                h8[q][j] = (short)bf16_rne_s(v);
            }
        }
        *(s16x8*)(&OPH[2][sr * 72 + sc0])     = h8[0];
        *(s16x8*)(&OPH[2][sr * 72 + sc0 + 8]) = h8[1];
    }
    __syncthreads();

    // ---- P5: pls = Wsr·r + N·bsr; T = A·G_b; then OP0 := T ----
    f32x4 accT[4];
    #pragma unroll
    for (int i = 0; i < 4; ++i) accT[i] = (f32x4){0.f, 0.f, 0.f, 0.f};
    if (t < 64) {
        float s = 0.f;
        for (int k = 0; k < 64; ++k) s += F1[t * 65 + k] * rl[k];
        pls[t] = s + 16384.f * sbv[t];
    }
    mm64(OPH[1], OPH[0], accT);
    __syncthreads();
    #pragma unroll
    for (int bj = 0; bj < 4; ++bj)
        #pragma unroll
        for (int j = 0; j < 4; ++j) {
            const int row = 16 * w + jg * 4 + j, col = 16 * bj + cl;
            OPH[0][row * 72 + col] = (unsigned short)bf16_rne_s(accT[bj][j]);
        }
    __syncthreads();

    // ---- P6: R = T·S^T + rank1; rowmax -> aml ----
    {
        f32x4 acc[4];
        #pragma unroll
        for (int i = 0; i < 4; ++i) acc[i] = (f32x4){0.f, 0.f, 0.f, 0.f};
        mm64(OPH[0], OPH[2], acc);
        float mx[4] = {-3.4e38f, -3.4e38f, -3.4e38f, -3.4e38f};
        #pragma unroll
        for (int j = 0; j < 4; ++j) {
            const int row = 16 * w + jg * 4 + j;
            const float ur = ul[row], ar = avs[row];
            #pragma unroll
            for (int bj = 0; bj < 4; ++bj) {
                const int col = 16 * bj + cl;
                const float v = acc[bj][j] + ur * sbv[col] + ar * pls[col];
                mx[j] = fmaxf(mx[j], v);
            }
        }
        #pragma unroll
        for (int m = 1; m <= 8; m <<= 1)
            #pragma unroll
            for (int j = 0; j < 4; ++j) mx[j] = fmaxf(mx[j], __shfl_xor(mx[j], m));
        if (cl == 0) {
            #pragma unroll
            for (int j = 0; j < 4; ++j) aml[16 * w + jg * 4 + j] = mx[j];
        }
    }
    __syncthreads();

    // ---- P7: w_b = Wc·aml ----
    if (t < 64) {
        float s = 0.f;
        for (int c = 0; c < 64; ++c) s += Wc[t * 64 + c] * aml[c];
        ws[WS_W + bb * 64 + t] = s;
    }
}

// ============ K3: out[b,o,n] = w[b,o] * v[b,n] (nontemporal, 2048 blocks) ============
__global__ __launch_bounds__(256) void k3(const float* __restrict__ ws, float* __restrict__ out) {
    const int blk = blockIdx.x;
    const int b = blk >> 6, seg = blk & 63;
    const int r0 = (seg >> 4) * 16, chk = seg & 15;
    __shared__ float wls[16];
    const int t = threadIdx.x;
    if (t < 16) wls[t] = ws[WS_W + b * 64 + r0 + t];
    __syncthreads();
    const size_t nb = (size_t)chk * 1024 + 4 * t;
    const f32x4 v4 = *(const f32x4*)(ws + WS_V + (size_t)b * N_ + nb);
    float* ob = out + ((size_t)b * C_ + r0) * N_ + nb;
    #pragma unroll
    for (int o = 0; o < 16; ++o) {
        __builtin_nontemporal_store(v4 * wls[o], (f32x4*)(ob + (size_t)o * N_));
    }
}

extern "C" void kernel_launch(void* const* d_in, const int* in_sizes, int n_in,
                              void* d_out, int out_size, void* d_ws, size_t ws_size,
                              hipStream_t stream) {
    const float* x     = (const float*)d_in[0];
    const float* Wq    = (const float*)d_in[1];
    const float* gamma = (const float*)d_in[3];
    const float* beta  = (const float*)d_in[4];
    const float* Wq2   = (const float*)d_in[5];
    const float* bq2   = (const float*)d_in[6];
    const float* Wsr   = (const float*)d_in[7];
    const float* bsr   = (const float*)d_in[8];
    const float* Wc    = (const float*)d_in[9];
    float* ws  = (float*)d_ws;
    float* out = (float*)d_out;

    hipLaunchKernelGGL(k1,  dim3(512),  dim3(256), 0, stream, x, ws);
    hipLaunchKernelGGL(k2a, dim3(256),  dim3(256), 0, stream, ws);
    hipLaunchKernelGGL(k2b, dim3(32),   dim3(256), 0, stream,
                       Wq, gamma, beta, Wq2, bq2, Wsr, bsr, Wc, ws);
    hipLaunchKernelGGL(k3,  dim3(2048), dim3(256), 0, stream, ws, out);
}

// Round 11
// 74.967 us; speedup vs baseline: 3.9236x; 1.5552x over previous
//
#include <hip/hip_runtime.h>
#include <hip/hip_bf16.h>

// Problem constants (B,C,N fixed by the reference)
#define B_ 32
#define C_ 64
#define N_ 16384
constexpr float BN_INV = 1.0f / (32.0f * 16384.0f);   // 1/(B*N)

typedef float f32x4 __attribute__((ext_vector_type(4)));
typedef short s16x8 __attribute__((ext_vector_type(8)));

// ---- workspace layout (float offsets) ----
constexpr size_t WS_GPART = 0;                               // [512][4096] per-(b,chunk) Gram partials
constexpr size_t WS_RPART = WS_GPART + (size_t)512 * 4096;   // [512][64]   rowsum partials
constexpr size_t WS_G     = WS_RPART + (size_t)512 * 64;     // [32][4096]  per-batch Gram
constexpr size_t WS_RB    = WS_G + (size_t)32 * 4096;        // [32][64]    per-batch rowsums
constexpr size_t WS_V     = WS_RB + (size_t)32 * 64;         // [32][16384] channel means
constexpr size_t WS_W     = WS_V + (size_t)32 * N_;          // [32][64]    w_b = Wc @ attnmax

__device__ constexpr int P1I[10] = {0,0,0,0,1,1,1,2,2,3};
__device__ constexpr int P1J[10] = {0,1,2,3,1,2,3,2,3,3};
__device__ constexpr int P1AT[4][4] = {{0,1,2,3},{1,4,5,6},{2,5,7,8},{3,6,8,9}};

__device__ __forceinline__ unsigned short bf16_rne_s(float f) {
    unsigned u = __float_as_uint(f);
    unsigned r = u + 0x7FFFu + ((u >> 16) & 1u);
    return (unsigned short)(r >> 16);
}
// HW packed f32->bf16 (RNE), 2 values per instruction.
__device__ __forceinline__ unsigned cvt_pk_bf16(float lo, float hi) {
    unsigned r;
    asm("v_cvt_pk_bf16_f32 %0, %1, %2" : "=v"(r) : "v"(lo), "v"(hi));
    return r;
}
__device__ __forceinline__ void cvt8hi(const f32x4& a, const f32x4& b, s16x8& hi) {
    union { unsigned w[4]; s16x8 v; } u;
    u.w[0] = cvt_pk_bf16(a[0], a[1]);
    u.w[1] = cvt_pk_bf16(a[2], a[3]);
    u.w[2] = cvt_pk_bf16(b[0], b[1]);
    u.w[3] = cvt_pk_bf16(b[2], b[3]);
    hi = u.v;
}

// ============ K1: barrier-free per-wave Gram (hi bf16 MFMA) + v + rowsums ============
// 512 blocks x 512 threads, __launch_bounds__(512,2): VGPR ~112, 2 blocks/CU (R7-proven).
__global__ __launch_bounds__(512, 2) void k1(const float* __restrict__ x, float* __restrict__ ws) {
    __shared__ __align__(16) float rawb[4][10 * 256];   // 40 KB
    __shared__ float rws[8][64];
    const int t = threadIdx.x, wv = t >> 6, lane = t & 63;
    const int b = blockIdx.x >> 4, ch = blockIdx.x & 15;
    const int kg = lane >> 4, cl = lane & 15;
    const float* xb = x + ((size_t)b * C_ + cl) * N_ + ch * 1024 + kg * 8;

    f32x4 accP1[10];
    #pragma unroll
    for (int i = 0; i < 10; ++i) accP1[i] = (f32x4){0.f, 0.f, 0.f, 0.f};
    f32x4 rs = {0.f, 0.f, 0.f, 0.f};

    f32x4 cA[4], cB[4], nA[4], nB[4];
    #pragma unroll
    for (int g = 0; g < 4; ++g) {
        cA[g] = *(const f32x4*)(xb + (size_t)g * (16 * N_) + wv * 32);
        cB[g] = *(const f32x4*)(xb + (size_t)g * (16 * N_) + wv * 32 + 4);
    }

    for (int w = 0; w < 4; ++w) {
        if (w < 3) {   // prefetch next window before any compute
            const int noff = (8 * (w + 1) + wv) * 32;
            #pragma unroll
            for (int g = 0; g < 4; ++g) {
                nA[g] = *(const f32x4*)(xb + (size_t)g * (16 * N_) + noff);
                nB[g] = *(const f32x4*)(xb + (size_t)g * (16 * N_) + noff + 4);
            }
        }
        s16x8 hi[4];
        #pragma unroll
        for (int g = 0; g < 4; ++g) cvt8hi(cA[g], cB[g], hi[g]);

        // v: sum over 64 channels = local over g + 16-lane butterfly
        f32x4 s0 = cA[0] + cA[1] + cA[2] + cA[3];
        f32x4 s1 = cB[0] + cB[1] + cB[2] + cB[3];
        #pragma unroll
        for (int m = 1; m <= 8; m <<= 1) {
            #pragma unroll
            for (int j = 0; j < 4; ++j) {
                s0[j] += __shfl_xor(s0[j], m);
                s1[j] += __shfl_xor(s1[j], m);
            }
        }
        if (cl == 0) {
            float* vp = ws + WS_V + (size_t)b * N_ + ch * 1024 + (8 * w + wv) * 32 + kg * 8;
            *(f32x4*)vp       = s0 * 0.015625f;
            *(f32x4*)(vp + 4) = s1 * 0.015625f;
        }
        // rowsums (lane-local)
        #pragma unroll
        for (int g = 0; g < 4; ++g)
            rs[g] += cA[g][0] + cA[g][1] + cA[g][2] + cA[g][3]
                   + cB[g][0] + cB[g][1] + cB[g][2] + cB[g][3];

        // Gram: P1 = Hi Hi^T (10 upper blocks)
        #pragma unroll
        for (int i = 0; i < 10; ++i)
            accP1[i] = __builtin_amdgcn_mfma_f32_16x16x32_bf16(hi[P1I[i]], hi[P1J[i]], accP1[i], 0, 0, 0);

        #pragma unroll
        for (int g = 0; g < 4; ++g) { cA[g] = nA[g]; cB[g] = nB[g]; }
    }

    // rowsum: fold k-groups
    #pragma unroll
    for (int g = 0; g < 4; ++g) {
        rs[g] += __shfl_xor(rs[g], 16);
        rs[g] += __shfl_xor(rs[g], 32);
    }
    if (lane < 16) {
        #pragma unroll
        for (int g = 0; g < 4; ++g) rws[wv][g * 16 + lane] = rs[g];
    }

    // G reduction tree
    if (wv < 4) {
        float* dst = rawb[wv];
        #pragma unroll
        for (int i = 0; i < 10; ++i) *(f32x4*)(dst + i * 256 + lane * 4) = accP1[i];
    }
    __syncthreads();
    if (wv >= 4) {
        float* dst = rawb[wv - 4];
        #pragma unroll
        for (int i = 0; i < 10; ++i) {
            f32x4 o = *(f32x4*)(dst + i * 256 + lane * 4);
            *(f32x4*)(dst + i * 256 + lane * 4) = o + accP1[i];
        }
    }
    __syncthreads();
    if (t < 64) {
        float s = 0.f;
        #pragma unroll
        for (int g = 0; g < 8; ++g) s += rws[g][t];
        ws[WS_RPART + (size_t)blockIdx.x * 64 + t] = s;
    }
    float* gp = ws + WS_GPART + (size_t)blockIdx.x * 4096;
    for (int e = t; e < 4096; e += 512) {
        const int r = e >> 6, c = e & 63;
        const int bi = r >> 4, bj = c >> 4, rr = r & 15, cc = c & 15;
        const int i1 = P1AT[bi][bj] * 256;
        const int o1 = (bi <= bj) ? (((rr >> 2) * 16 + cc) * 4 + (rr & 3))
                                  : (((cc >> 2) * 16 + rr) * 4 + (cc & 3));
        gp[e] = rawb[0][i1 + o1] + rawb[1][i1 + o1] + rawb[2][i1 + o1] + rawb[3][i1 + o1];
    }
}

// ============ K2a: reduce chunk partials -> per-batch G, r ============
__global__ __launch_bounds__(256) void k2a(float* __restrict__ ws) {
    const int b = blockIdx.x >> 3, sl = blockIdx.x & 7, t = threadIdx.x;
    #pragma unroll
    for (int h = 0; h < 2; ++h) {
        const int e = sl * 512 + h * 256 + t;
        float s = 0.f;
        for (int chn = 0; chn < 16; ++chn) s += ws[WS_GPART + ((size_t)(b * 16 + chn)) * 4096 + e];
        ws[WS_G + (size_t)b * 4096 + e] = s;
    }
    if (sl == 0 && t < 64) {
        float s = 0.f;
        for (int chn = 0; chn < 16; ++chn) s += ws[WS_RPART + (size_t)(b * 16 + chn) * 64 + t];
        ws[WS_RB + b * 64 + t] = s;
    }
}

// ============ K2b: MFMA-based C×C algebra (hh-only bf16), one block per batch ============
__global__ __launch_bounds__(256) void k2b(const float* __restrict__ Wq, const float* __restrict__ gamma,
                                           const float* __restrict__ beta, const float* __restrict__ Wq2,
                                           const float* __restrict__ bq2, const float* __restrict__ Wsr,
                                           const float* __restrict__ bsr, const float* __restrict__ Wc,
                                           float* __restrict__ ws) {
    __shared__ __align__(16) unsigned short OPH[3][64 * 72];   // bf16 operand slots (27.6 KB)
    __shared__ float F1[64 * 65], F2[64 * 65];
    __shared__ float mS[64], muS[64], DS[64], abv[64], quadS[64];
    __shared__ float rl[64], ul[64], avs[64], sbv[64], pls[64], aml[64];
    const int bb = blockIdx.x, t = threadIdx.x;
    const int w = t >> 6, lane = t & 63, cl = lane & 15, jg = lane >> 4;
    const int sr = t >> 2, sc0 = (t & 3) * 16;

    // ---- P0: stage Gbar->OP0, Wq->F1+OP1, Wq2->F2+OP2, vectors ----
    {
        f32x4 s[4];
        #pragma unroll
        for (int j = 0; j < 4; ++j) s[j] = (f32x4){0.f, 0.f, 0.f, 0.f};
        for (int b = 0; b < 32; ++b) {
            const float* gbp = ws + WS_G + (size_t)b * 4096 + sr * 64 + sc0;
            #pragma unroll
            for (int j = 0; j < 4; ++j) s[j] += *(const f32x4*)(gbp + 4 * j);
        }
        s16x8 h8[2];
        #pragma unroll
        for (int q = 0; q < 2; ++q)
            #pragma unroll
            for (int j = 0; j < 8; ++j)
                h8[q][j] = (short)bf16_rne_s(s[q * 2 + (j >> 2)][j & 3] * BN_INV);
        *(s16x8*)(&OPH[0][sr * 72 + sc0])     = h8[0];
        *(s16x8*)(&OPH[0][sr * 72 + sc0 + 8]) = h8[1];
    }
    #pragma unroll
    for (int mtx = 0; mtx < 2; ++mtx) {
        const float* src = (mtx == 0 ? Wq : Wq2) + sr * 64 + sc0;
        float* F = (mtx == 0) ? F1 : F2;
        s16x8 h8[2];
        #pragma unroll
        for (int q = 0; q < 2; ++q) {
            f32x4 a = *(const f32x4*)(src + q * 8);
            f32x4 b = *(const f32x4*)(src + q * 8 + 4);
            #pragma unroll
            for (int j = 0; j < 8; ++j) {
                float v = (j < 4) ? a[j] : b[j - 4];
                F[sr * 65 + sc0 + q * 8 + j] = v;
                h8[q][j] = (short)bf16_rne_s(v);
            }
        }
        unsigned short* H = OPH[1 + mtx];
        *(s16x8*)(&H[sr * 72 + sc0])     = h8[0];
        *(s16x8*)(&H[sr * 72 + sc0 + 8]) = h8[1];
    }
    if (t < 64) {
        float sm = 0.f;
        for (int b = 0; b < 32; ++b) sm += ws[WS_RB + b * 64 + t];
        mS[t] = sm * BN_INV;
        rl[t] = ws[WS_RB + bb * 64 + t];
        sbv[t] = bsr[t];
    }
    __syncthreads();

    auto mm64 = [&](const unsigned short* AH, const unsigned short* BH, f32x4 acc[4]) {
        #pragma unroll
        for (int ks = 0; ks < 2; ++ks) {
            const int ko = ks * 32 + jg * 8;
            s16x8 ah = *(const s16x8*)(AH + (16 * w + cl) * 72 + ko);
            #pragma unroll
            for (int bj = 0; bj < 4; ++bj) {
                s16x8 bh = *(const s16x8*)(BH + (16 * bj + cl) * 72 + ko);
                acc[bj] = __builtin_amdgcn_mfma_f32_16x16x32_bf16(ah, bh, acc[bj], 0, 0, 0);
            }
        }
    };
    // acc element (bj, j) sits at (row = 16w + jg*4 + j, col = 16bj + cl)

    // ---- P1: Y = Wq·Gbar; quad_o = rowdot(Y, Wq); mu0 = Wq·m ----
    {
        f32x4 acc[4];
        #pragma unroll
        for (int i = 0; i < 4; ++i) acc[i] = (f32x4){0.f, 0.f, 0.f, 0.f};
        mm64(OPH[1], OPH[0], acc);
        float s[4] = {0.f, 0.f, 0.f, 0.f};
        #pragma unroll
        for (int j = 0; j < 4; ++j) {
            const int row = 16 * w + jg * 4 + j;
            #pragma unroll
            for (int bj = 0; bj < 4; ++bj) s[j] += acc[bj][j] * F1[row * 65 + 16 * bj + cl];
        }
        #pragma unroll
        for (int m = 1; m <= 8; m <<= 1)
            #pragma unroll
            for (int j = 0; j < 4; ++j) s[j] += __shfl_xor(s[j], m);
        if (cl == 0) {
            #pragma unroll
            for (int j = 0; j < 4; ++j) quadS[16 * w + jg * 4 + j] = s[j];
        }
        if (t < 64) {
            float s2 = 0.f;
            for (int c = 0; c < 64; ++c) s2 += F1[t * 65 + c] * mS[c];
            muS[t] = s2;
        }
    }
    __syncthreads();

    // ---- P2: D, abv; OP0 := (D∘Wq)^T; avs = Wq2·abv + bq2 ----
    if (t < 64) {
        const float var = quadS[t] - muS[t] * muS[t];
        const float D = gamma[t] * rsqrtf(var + 1e-5f);
        DS[t] = D;
        abv[t] = beta[t] - D * muS[t];
    }
    __syncthreads();
    {
        s16x8 h8[2];
        #pragma unroll
        for (int q = 0; q < 2; ++q)
            #pragma unroll
            for (int j = 0; j < 8; ++j) {
                const int c = sc0 + q * 8 + j;
                h8[q][j] = (short)bf16_rne_s(DS[c] * F1[c * 65 + sr]);
            }
        *(s16x8*)(&OPH[0][sr * 72 + sc0])     = h8[0];
        *(s16x8*)(&OPH[0][sr * 72 + sc0 + 8]) = h8[1];
    }
    if (t < 64) {
        float s = 0.f;
        for (int k = 0; k < 64; ++k) s += F2[t * 65 + k] * abv[k];
        avs[t] = s + bq2[t];
    }
    __syncthreads();

    // ---- P3: A = Wq2·(DWq); u = A·r; OP1 := A ----
    {
        f32x4 acc[4];
        #pragma unroll
        for (int i = 0; i < 4; ++i) acc[i] = (f32x4){0.f, 0.f, 0.f, 0.f};
        mm64(OPH[2], OPH[0], acc);
        float s[4] = {0.f, 0.f, 0.f, 0.f};
        #pragma unroll
        for (int bj = 0; bj < 4; ++bj) {
            const float cv = rl[16 * bj + cl];
            #pragma unroll
            for (int j = 0; j < 4; ++j) s[j] += acc[bj][j] * cv;
        }
        #pragma unroll
        for (int m = 1; m <= 8; m <<= 1)
            #pragma unroll
            for (int j = 0; j < 4; ++j) s[j] += __shfl_xor(s[j], m);
        if (cl == 0) {
            #pragma unroll
            for (int j = 0; j < 4; ++j) ul[16 * w + jg * 4 + j] = s[j];
        }
        #pragma unroll
        for (int bj = 0; bj < 4; ++bj)
            #pragma unroll
            for (int j = 0; j < 4; ++j) {
                const int row = 16 * w + jg * 4 + j, col = 16 * bj + cl;
                OPH[1][row * 72 + col] = (unsigned short)bf16_rne_s(acc[bj][j]);
            }
    }
    __syncthreads();

    // ---- P4: OP0 := G_b rows; OP2 := Wsr rows (+F1 f32) ----
    {
        const float* gbp = ws + WS_G + (size_t)bb * 4096 + sr * 64 + sc0;
        s16x8 h8[2];
        #pragma unroll
        for (int q = 0; q < 2; ++q) {
            f32x4 a = *(const f32x4*)(gbp + q * 8);
            f32x4 b = *(const f32x4*)(gbp + q * 8 + 4);
            #pragma unroll
            for (int j = 0; j < 8; ++j)
                h8[q][j] = (short)bf16_rne_s((j < 4) ? a[j] : b[j - 4]);
        }
        *(s16x8*)(&OPH[0][sr * 72 + sc0])     = h8[0];
        *(s16x8*)(&OPH[0][sr * 72 + sc0 + 8]) = h8[1];
        const float* ssrc = Wsr + sr * 64 + sc0;
        #pragma unroll
        for (int q = 0; q < 2; ++q) {
            f32x4 a = *(const f32x4*)(ssrc + q * 8);
            f32x4 b = *(const f32x4*)(ssrc + q * 8 + 4);
            #pragma unroll
            for (int j = 0; j < 8; ++j) {
                float v = (j < 4) ? a[j] : b[j - 4];
                F1[sr * 65 + sc0 + q * 8 + j] = v;
                h8[q][j] = (short)bf16_rne_s(v);
            }
        }
        *(s16x8*)(&OPH[2][sr * 72 + sc0])     = h8[0];
        *(s16x8*)(&OPH[2][sr * 72 + sc0 + 8]) = h8[1];
    }
    __syncthreads();

    // ---- P5: pls = Wsr·r + N·bsr; T = A·G_b; then OP0 := T ----
    f32x4 accT[4];
    #pragma unroll
    for (int i = 0; i < 4; ++i) accT[i] = (f32x4){0.f, 0.f, 0.f, 0.f};
    if (t < 64) {
        float s = 0.f;
        for (int k = 0; k < 64; ++k) s += F1[t * 65 + k] * rl[k];
        pls[t] = s + 16384.f * sbv[t];
    }
    mm64(OPH[1], OPH[0], accT);
    __syncthreads();
    #pragma unroll
    for (int bj = 0; bj < 4; ++bj)
        #pragma unroll
        for (int j = 0; j < 4; ++j) {
            const int row = 16 * w + jg * 4 + j, col = 16 * bj + cl;
            OPH[0][row * 72 + col] = (unsigned short)bf16_rne_s(accT[bj][j]);
        }
    __syncthreads();

    // ---- P6: R = T·S^T + rank1; rowmax -> aml ----
    {
        f32x4 acc[4];
        #pragma unroll
        for (int i = 0; i < 4; ++i) acc[i] = (f32x4){0.f, 0.f, 0.f, 0.f};
        mm64(OPH[0], OPH[2], acc);
        float mx[4] = {-3.4e38f, -3.4e38f, -3.4e38f, -3.4e38f};
        #pragma unroll
        for (int j = 0; j < 4; ++j) {
            const int row = 16 * w + jg * 4 + j;
            const float ur = ul[row], ar = avs[row];
            #pragma unroll
            for (int bj = 0; bj < 4; ++bj) {
                const int col = 16 * bj + cl;
                const float v = acc[bj][j] + ur * sbv[col] + ar * pls[col];
                mx[j] = fmaxf(mx[j], v);
            }
        }
        #pragma unroll
        for (int m = 1; m <= 8; m <<= 1)
            #pragma unroll
            for (int j = 0; j < 4; ++j) mx[j] = fmaxf(mx[j], __shfl_xor(mx[j], m));
        if (cl == 0) {
            #pragma unroll
            for (int j = 0; j < 4; ++j) aml[16 * w + jg * 4 + j] = mx[j];
        }
    }
    __syncthreads();

    // ---- P7: w_b = Wc·aml ----
    if (t < 64) {
        float s = 0.f;
        for (int c = 0; c < 64; ++c) s += Wc[t * 64 + c] * aml[c];
        ws[WS_W + bb * 64 + t] = s;
    }
}

// ============ K3: out[b,o,n] = w[b,o] * v[b,n] (nontemporal, 2048 blocks) ============
__global__ __launch_bounds__(256) void k3(const float* __restrict__ ws, float* __restrict__ out) {
    const int blk = blockIdx.x;
    const int b = blk >> 6, seg = blk & 63;
    const int r0 = (seg >> 4) * 16, chk = seg & 15;
    __shared__ float wls[16];
    const int t = threadIdx.x;
    if (t < 16) wls[t] = ws[WS_W + b * 64 + r0 + t];
    __syncthreads();
    const size_t nb = (size_t)chk * 1024 + 4 * t;
    const f32x4 v4 = *(const f32x4*)(ws + WS_V + (size_t)b * N_ + nb);
    float* ob = out + ((size_t)b * C_ + r0) * N_ + nb;
    #pragma unroll
    for (int o = 0; o < 16; ++o) {
        __builtin_nontemporal_store(v4 * wls[o], (f32x4*)(ob + (size_t)o * N_));
    }
}

extern "C" void kernel_launch(void* const* d_in, const int* in_sizes, int n_in,
                              void* d_out, int out_size, void* d_ws, size_t ws_size,
                              hipStream_t stream) {
    const float* x     = (const float*)d_in[0];
    const float* Wq    = (const float*)d_in[1];
    const float* gamma = (const float*)d_in[3];
    const float* beta  = (const float*)d_in[4];
    const float* Wq2   = (const float*)d_in[5];
    const float* bq2   = (const float*)d_in[6];
    const float* Wsr   = (const float*)d_in[7];
    const float* bsr   = (const float*)d_in[8];
    const float* Wc    = (const float*)d_in[9];
    float* ws  = (float*)d_ws;
    float* out = (float*)d_out;

    hipLaunchKernelGGL(k1,  dim3(512),  dim3(512), 0, stream, x, ws);
    hipLaunchKernelGGL(k2a, dim3(256),  dim3(256), 0, stream, ws);
    hipLaunchKernelGGL(k2b, dim3(32),   dim3(256), 0, stream,
                       Wq, gamma, beta, Wq2, bq2, Wsr, bsr, Wc, ws);
    hipLaunchKernelGGL(k3,  dim3(2048), dim3(256), 0, stream, ws, out);
}